// Round 1
// baseline (518.898 us; speedup 1.0000x reference)
//
#include <hip/hip_runtime.h>

// Problem constants (from reference setup_inputs): B=4, N=M=4096, D=128.
// d_out layout (floats): match_mask [4*4096*4096] | pairs [16384] (as float) | top_dists [16384]
// ws layout (floats):    x2 [16384] | y2 [16384] | pvals [32768] | pidx [32768 ints]

__global__ __launch_bounds__(256) void k_rowsq(const float* __restrict__ xd,
                                               const float* __restrict__ yd,
                                               float* __restrict__ ws) {
    int tid  = threadIdx.x;
    int wid  = tid >> 6, lane = tid & 63;
    int gr   = blockIdx.x * 4 + wid;                 // 0..32767
    const float* src = (gr < 16384) ? (xd + (size_t)gr * 128)
                                    : (yd + (size_t)(gr - 16384) * 128);
    float2 v = reinterpret_cast<const float2*>(src)[lane];
    float s  = v.x * v.x + v.y * v.y;
    for (int off = 32; off > 0; off >>= 1) s += __shfl_down(s, off);
    if (lane == 0) ws[gr] = s;
}

__global__ __launch_bounds__(256, 1) void k_main(const float* __restrict__ xd,
                                                 const float* __restrict__ yd,
                                                 const float* __restrict__ mask,
                                                 const float* __restrict__ ws,
                                                 float* __restrict__ pvals,
                                                 int* __restrict__ pidx,
                                                 float* __restrict__ mm) {
    __shared__ __align__(16) float Xs[128 * 128];
    __shared__ __align__(16) float Ys[128 * 128];

    const int bid  = blockIdx.x;
    const int mh   = bid & 1;          // M half
    const int rb   = (bid >> 1) & 31;  // row block
    const int b    = bid >> 6;         // batch
    const int tid  = threadIdx.x;
    const int ty   = tid >> 4;         // 0..15
    const int tx   = tid & 15;         // 0..15
    const int row0 = rb * 128;
    const int m0   = mh * 2048;

    // ---- fused zeroing of our match_mask region: 128 rows x 2048 cols ----
    {
        const float4 z = make_float4(0.f, 0.f, 0.f, 0.f);
        size_t base = ((size_t)(b * 4096 + row0)) * 4096 + (size_t)m0;
        for (int r = 0; r < 128; ++r) {
            float4* p = reinterpret_cast<float4*>(mm + base + (size_t)r * 4096);
            p[tid]       = z;
            p[tid + 256] = z;
        }
    }

    // ---- stage X tile (128 rows x 128 k), XOR-swizzled float4 slots ----
    {
        int lrow = tid >> 5;   // 0..7
        int slot = tid & 31;   // 0..31 (float4 slot)
        for (int p = 0; p < 16; ++p) {
            int row  = p * 8 + lrow;
            float4 v = reinterpret_cast<const float4*>(
                           xd + ((size_t)(b * 4096 + row0 + row)) * 128)[slot];
            int ss = slot ^ (row & 31);
            *reinterpret_cast<float4*>(&Xs[row * 128 + (ss << 2)]) = v;
        }
    }

    float x2r[8];
    #pragma unroll
    for (int i = 0; i < 8; ++i) x2r[i] = ws[b * 4096 + row0 + ty * 8 + i];
    const float* y2g = ws + 16384 + b * 4096;

    float bv[8];
    int   bi[8];
    #pragma unroll
    for (int i = 0; i < 8; ++i) { bv[i] = 3.4e38f; bi[i] = 0; }

    __syncthreads();

    for (int tile = 0; tile < 16; ++tile) {
        const int mbase = m0 + tile * 128;

        // ---- stage Y tile ----
        {
            int lrow = tid >> 5;
            int slot = tid & 31;
            for (int p = 0; p < 16; ++p) {
                int row  = p * 8 + lrow;
                float4 v = reinterpret_cast<const float4*>(
                               yd + ((size_t)(b * 4096 + mbase + row)) * 128)[slot];
                int ss = slot ^ (row & 31);
                *reinterpret_cast<float4*>(&Ys[row * 128 + (ss << 2)]) = v;
            }
        }
        __syncthreads();

        // ---- 8x8 register-tiled dot products over K=128 ----
        float acc[8][8];
        #pragma unroll
        for (int i = 0; i < 8; ++i)
            #pragma unroll
            for (int j = 0; j < 8; ++j) acc[i][j] = 0.0f;

        #pragma unroll 4
        for (int ks = 0; ks < 32; ++ks) {
            float4 bf[8];
            #pragma unroll
            for (int j = 0; j < 8; ++j) {
                int c = j * 16 + tx;
                bf[j] = *reinterpret_cast<const float4*>(
                            &Ys[c * 128 + ((ks ^ (c & 31)) << 2)]);
            }
            #pragma unroll
            for (int i = 0; i < 8; ++i) {
                int r   = ty * 8 + i;
                float4 a = *reinterpret_cast<const float4*>(
                               &Xs[r * 128 + ((ks ^ (r & 31)) << 2)]);
                #pragma unroll
                for (int j = 0; j < 8; ++j) {
                    acc[i][j] = fmaf(a.x, bf[j].x, acc[i][j]);
                    acc[i][j] = fmaf(a.y, bf[j].y, acc[i][j]);
                    acc[i][j] = fmaf(a.z, bf[j].z, acc[i][j]);
                    acc[i][j] = fmaf(a.w, bf[j].w, acc[i][j]);
                }
            }
        }

        // ---- epilogue: d2 -> dist*mask -> running argmin ----
        float y2v[8];
        #pragma unroll
        for (int j = 0; j < 8; ++j) y2v[j] = y2g[mbase + j * 16 + tx];

        #pragma unroll
        for (int i = 0; i < 8; ++i) {
            int r = ty * 8 + i;
            const float* mr = mask + ((size_t)(b * 4096 + row0 + r)) * 4096;
            #pragma unroll
            for (int j = 0; j < 8; ++j) {
                int   m  = mbase + j * 16 + tx;
                float d2 = x2r[i] + y2v[j] - 2.0f * acc[i][j];
                float d  = sqrtf(fmaxf(d2, 0.0f)) * mr[m];
                if (d < bv[i]) { bv[i] = d; bi[i] = m; }   // first-occurrence kept
            }
        }
        __syncthreads();
    }

    // ---- block-level merge across the 16 tx threads per row ----
    float* candv = Xs;                                   // [128][16]
    int*   candi = reinterpret_cast<int*>(Xs + 2048);    // [128][16]
    #pragma unroll
    for (int i = 0; i < 8; ++i) {
        int r = ty * 8 + i;
        candv[r * 16 + tx] = bv[i];
        candi[r * 16 + tx] = bi[i];
    }
    __syncthreads();
    if (tid < 128) {
        int   r  = tid;
        float v  = candv[r * 16];
        int   ix = candi[r * 16];
        for (int t = 1; t < 16; ++t) {
            float v2 = candv[r * 16 + t];
            int   i2 = candi[r * 16 + t];
            if (v2 < v || (v2 == v && i2 < ix)) { v = v2; ix = i2; }
        }
        int grow = b * 4096 + row0 + r;
        pvals[grow * 2 + mh] = v;
        pidx [grow * 2 + mh] = ix;
    }
}

__global__ __launch_bounds__(256) void k_fin(const float* __restrict__ pvals,
                                             const int* __restrict__ pidx,
                                             float* __restrict__ out) {
    int t = blockIdx.x * 256 + threadIdx.x;   // 0..16383 = b*4096+n
    float v0 = pvals[t * 2],     v1 = pvals[t * 2 + 1];
    int   i0 = pidx [t * 2],     i1 = pidx [t * 2 + 1];
    bool take1 = (v1 < v0) || (v1 == v0 && i1 < i0);
    float v  = take1 ? v1 : v0;
    int   ix = take1 ? i1 : i0;
    out[67108864 + t]         = (float)ix;            // pairs (as float)
    out[67108864 + 16384 + t] = v;                    // top_dists
    out[(size_t)t * 4096 + (size_t)ix] = 1.0f;        // match_mask one-hot
}

extern "C" void kernel_launch(void* const* d_in, const int* in_sizes, int n_in,
                              void* d_out, int out_size, void* d_ws, size_t ws_size,
                              hipStream_t stream) {
    const float* xd   = (const float*)d_in[0];
    const float* yd   = (const float*)d_in[1];
    const float* mask = (const float*)d_in[2];
    float* out   = (float*)d_out;
    float* wsf   = (float*)d_ws;
    float* pvals = wsf + 32768;
    int*   pidx  = (int*)(wsf + 65536);

    k_rowsq<<<8192, 256, 0, stream>>>(xd, yd, wsf);
    k_main <<<256,  256, 0, stream>>>(xd, yd, mask, wsf, pvals, pidx, out);
    k_fin  <<<64,   256, 0, stream>>>(pvals, pidx, out);
}

// Round 2
// 479.141 us; speedup vs baseline: 1.0830x; 1.0830x over previous
//
#include <hip/hip_runtime.h>

// B=4, N=M=4096, D=128.
// d_out (floats): match_mask [4*4096*4096] | pairs [16384] (as float) | top_dists [16384]
// ws (new path): x2 [16384] f32 | y2 [16384] f32 | planes: 2 inputs x 3 planes x 4x4096x128 bf16
//   plane element offset: ((((i*3+p)*4 + b)*256 + rblk)*4 + kb)*512 + l*8 + e
//   holding value input[b][rblk*16 + (l&15)][kb*32 + (l>>4)*8 + e]  (k-order consistent A/B -> cancels)

typedef float  f32x4  __attribute__((ext_vector_type(4)));
typedef short  bf16x8 __attribute__((ext_vector_type(8)));

__device__ __forceinline__ unsigned short f2bf(float x) {
    unsigned u = __float_as_uint(x);
    u += 0x7FFFu + ((u >> 16) & 1u);
    return (unsigned short)(u >> 16);
}
__device__ __forceinline__ float bf2f(unsigned short s) {
    return __uint_as_float(((unsigned)s) << 16);
}

__global__ __launch_bounds__(256) void k_rowsq(const float* __restrict__ xd,
                                               const float* __restrict__ yd,
                                               float* __restrict__ ws) {
    int tid  = threadIdx.x;
    int wid  = tid >> 6, lane = tid & 63;
    int gr   = blockIdx.x * 4 + wid;                 // 0..32767
    const float* src = (gr < 16384) ? (xd + (size_t)gr * 128)
                                    : (yd + (size_t)(gr - 16384) * 128);
    float2 v = reinterpret_cast<const float2*>(src)[lane];
    float s  = v.x * v.x + v.y * v.y;
    for (int off = 32; off > 0; off >>= 1) s += __shfl_down(s, off);
    if (lane == 0) ws[gr] = s;
}

// ---- split f32 -> 3 bf16 planes, packed in MFMA fragment order ----
__global__ __launch_bounds__(256) void k_prep(const float* __restrict__ xd,
                                              const float* __restrict__ yd,
                                              unsigned short* __restrict__ pl) {
    int bid  = blockIdx.x;            // 0..2047
    int i    = bid >> 10;             // input 0=x,1=y
    int b    = (bid >> 8) & 3;
    int rblk = bid & 255;
    int tid  = threadIdx.x;
    int kb   = tid >> 6;              // 0..3
    int l    = tid & 63;
    int r    = rblk * 16 + (l & 15);
    int k0   = kb * 32 + ((l >> 4) & 3) * 8;
    const float* src = (i ? yd : xd) + ((size_t)(b * 4096 + r) * 128 + k0);
    float v[8];
    *reinterpret_cast<float4*>(v)     = *reinterpret_cast<const float4*>(src);
    *reinterpret_cast<float4*>(v + 4) = *reinterpret_cast<const float4*>(src + 4);
    bf16x8 hv, mv, lv;
    #pragma unroll
    for (int e = 0; e < 8; ++e) {
        float x = v[e];
        unsigned short h  = f2bf(x);
        float r1 = x - bf2f(h);
        unsigned short m  = f2bf(r1);
        float r2 = r1 - bf2f(m);
        unsigned short lo = f2bf(r2);
        hv[e] = (short)h; mv[e] = (short)m; lv[e] = (short)lo;
    }
    const size_t PS = (size_t)4 * 256 * 4 * 512;   // plane stride (elements)
    size_t base = ((((size_t)(i * 3) * 4 + b) * 256 + rblk) * 4 + kb) * 512 + (size_t)l * 8;
    *reinterpret_cast<bf16x8*>(pl + base)          = hv;
    *reinterpret_cast<bf16x8*>(pl + base + PS)     = mv;
    *reinterpret_cast<bf16x8*>(pl + base + 2 * PS) = lv;
}

// ---- main: bf16x3 MFMA distance GEMM + fused argmin + fused mm zero/one-hot ----
__global__ __launch_bounds__(512, 2) void k_mfma(const float* __restrict__ mask,
                                                 const float* __restrict__ ws,
                                                 const unsigned short* __restrict__ pl,
                                                 float* __restrict__ out) {
    __shared__ float candv[8][64];
    __shared__ int   candi[8][64];

    const int bid = blockIdx.x;            // 256 blocks
    const int xcd = bid & 7, sub = bid >> 3;
    const int b   = xcd >> 1;              // batch: one per XCD pair (L2 locality for Y planes)
    const int rp  = (xcd & 1) * 32 + sub;  // 64-row panel 0..63
    const int tid = threadIdx.x;
    const int w   = tid >> 6;              // wave 0..7
    const int l   = tid & 63;
    const int g0  = b * 4096 + rp * 64;    // first global row

    // ---- fused zero of our match_mask slice (overlaps with compute) ----
    {
        const float4 z = make_float4(0.f, 0.f, 0.f, 0.f);
        float4* p = reinterpret_cast<float4*>(out + (size_t)g0 * 4096);
        for (int r = 0; r < 64; ++r) {
            float4* q = p + (size_t)r * 1024;
            q[tid] = z; q[tid + 512] = z;
        }
    }

    float x2r[16];
    #pragma unroll
    for (int mi = 0; mi < 4; ++mi)
        #pragma unroll
        for (int rg = 0; rg < 4; ++rg)
            x2r[mi * 4 + rg] = ws[g0 + mi * 16 + ((l >> 4) & 3) * 4 + rg];
    const float* y2 = ws + 16384 + b * 4096;

    float bv[16];
    int   bi[16];
    #pragma unroll
    for (int q = 0; q < 16; ++q) { bv[q] = 3.4e38f; bi[q] = 0; }

    for (int tile = 0; tile < 8; ++tile) {         // 8 tiles of 512 cols
        f32x4 acc[4][4];
        #pragma unroll
        for (int mi = 0; mi < 4; ++mi)
            #pragma unroll
            for (int ni = 0; ni < 4; ++ni) acc[mi][ni] = (f32x4){0.f, 0.f, 0.f, 0.f};

        #pragma unroll
        for (int kb = 0; kb < 4; ++kb) {
            bf16x8 A[3][4];
            #pragma unroll
            for (int p = 0; p < 3; ++p)
                #pragma unroll
                for (int mi = 0; mi < 4; ++mi)
                    A[p][mi] = *reinterpret_cast<const bf16x8*>(
                        pl + ((((size_t)p * 4 + b) * 256 + rp * 4 + mi) * 4 + kb) * 512 + (size_t)l * 8);
            #pragma unroll
            for (int ni = 0; ni < 4; ++ni) {
                const size_t cb = (size_t)tile * 32 + w * 4 + ni;
                bf16x8 Bh = *reinterpret_cast<const bf16x8*>(
                    pl + ((((size_t)3 * 4 + b) * 256 + cb) * 4 + kb) * 512 + (size_t)l * 8);
                bf16x8 Bm = *reinterpret_cast<const bf16x8*>(
                    pl + ((((size_t)4 * 4 + b) * 256 + cb) * 4 + kb) * 512 + (size_t)l * 8);
                bf16x8 Bl = *reinterpret_cast<const bf16x8*>(
                    pl + ((((size_t)5 * 4 + b) * 256 + cb) * 4 + kb) * 512 + (size_t)l * 8);
                #pragma unroll
                for (int mi = 0; mi < 4; ++mi) {
                    f32x4 c = acc[mi][ni];
                    c = __builtin_amdgcn_mfma_f32_16x16x32_bf16(A[0][mi], Bh, c, 0, 0, 0);
                    c = __builtin_amdgcn_mfma_f32_16x16x32_bf16(A[0][mi], Bm, c, 0, 0, 0);
                    c = __builtin_amdgcn_mfma_f32_16x16x32_bf16(A[1][mi], Bh, c, 0, 0, 0);
                    c = __builtin_amdgcn_mfma_f32_16x16x32_bf16(A[1][mi], Bm, c, 0, 0, 0);
                    c = __builtin_amdgcn_mfma_f32_16x16x32_bf16(A[0][mi], Bl, c, 0, 0, 0);
                    c = __builtin_amdgcn_mfma_f32_16x16x32_bf16(A[2][mi], Bh, c, 0, 0, 0);
                    acc[mi][ni] = c;
                }
            }
        }

        // ---- epilogue: d2 -> dist*mask -> running argmin ----
        #pragma unroll
        for (int ni = 0; ni < 4; ++ni) {
            int c = tile * 512 + w * 64 + ni * 16 + (l & 15);
            float y2v = y2[c];
            #pragma unroll
            for (int mi = 0; mi < 4; ++mi) {
                #pragma unroll
                for (int rg = 0; rg < 4; ++rg) {
                    int rl  = mi * 16 + ((l >> 4) & 3) * 4 + rg;
                    float d2 = x2r[mi * 4 + rg] + y2v - 2.0f * acc[mi][ni][rg];
                    float d  = sqrtf(fmaxf(d2, 0.0f)) * mask[(size_t)(g0 + rl) * 4096 + c];
                    int q = mi * 4 + rg;
                    if (d < bv[q]) { bv[q] = d; bi[q] = c; }
                }
            }
        }
    }

    // ---- merge across the 16 lanes (same l>>4 group share rows) ----
    #pragma unroll
    for (int off = 1; off < 16; off <<= 1) {
        #pragma unroll
        for (int q = 0; q < 16; ++q) {
            float ov = __shfl_xor(bv[q], off);
            int   oi = __shfl_xor(bi[q], off);
            if (ov < bv[q] || (ov == bv[q] && oi < bi[q])) { bv[q] = ov; bi[q] = oi; }
        }
    }
    if ((l & 15) == 0) {
        #pragma unroll
        for (int mi = 0; mi < 4; ++mi)
            #pragma unroll
            for (int rg = 0; rg < 4; ++rg) {
                int rl = mi * 16 + ((l >> 4) & 3) * 4 + rg;
                candv[w][rl] = bv[mi * 4 + rg];
                candi[w][rl] = bi[mi * 4 + rg];
            }
    }
    __syncthreads();

    if (tid < 64) {
        float v  = candv[0][tid];
        int   ix = candi[0][tid];
        #pragma unroll
        for (int ww = 1; ww < 8; ++ww) {
            float v2 = candv[ww][tid];
            int   i2 = candi[ww][tid];
            if (v2 < v || (v2 == v && i2 < ix)) { v = v2; ix = i2; }
        }
        int g = g0 + tid;
        out[67108864 + g]         = (float)ix;            // pairs
        out[67108864 + 16384 + g] = v;                    // top_dists
        out[(size_t)g * 4096 + (size_t)ix] = 1.0f;        // one-hot (our slice, zeroed above)
    }
}

// ================= fallback path (round-1 kernels, needs only 384 KB ws) =================
__global__ __launch_bounds__(256, 1) void k_main_fb(const float* __restrict__ xd,
                                                    const float* __restrict__ yd,
                                                    const float* __restrict__ mask,
                                                    const float* __restrict__ ws,
                                                    float* __restrict__ pvals,
                                                    int* __restrict__ pidx,
                                                    float* __restrict__ mm) {
    __shared__ __align__(16) float Xs[128 * 128];
    __shared__ __align__(16) float Ys[128 * 128];
    const int bid  = blockIdx.x;
    const int mh   = bid & 1;
    const int rb   = (bid >> 1) & 31;
    const int b    = bid >> 6;
    const int tid  = threadIdx.x;
    const int ty   = tid >> 4;
    const int tx   = tid & 15;
    const int row0 = rb * 128;
    const int m0   = mh * 2048;
    {
        const float4 z = make_float4(0.f, 0.f, 0.f, 0.f);
        size_t base = ((size_t)(b * 4096 + row0)) * 4096 + (size_t)m0;
        for (int r = 0; r < 128; ++r) {
            float4* p = reinterpret_cast<float4*>(mm + base + (size_t)r * 4096);
            p[tid] = z; p[tid + 256] = z;
        }
    }
    {
        int lrow = tid >> 5, slot = tid & 31;
        for (int p = 0; p < 16; ++p) {
            int row  = p * 8 + lrow;
            float4 v = reinterpret_cast<const float4*>(
                           xd + ((size_t)(b * 4096 + row0 + row)) * 128)[slot];
            int ss = slot ^ (row & 31);
            *reinterpret_cast<float4*>(&Xs[row * 128 + (ss << 2)]) = v;
        }
    }
    float x2r[8];
    #pragma unroll
    for (int i = 0; i < 8; ++i) x2r[i] = ws[b * 4096 + row0 + ty * 8 + i];
    const float* y2g = ws + 16384 + b * 4096;
    float bv[8]; int bi[8];
    #pragma unroll
    for (int i = 0; i < 8; ++i) { bv[i] = 3.4e38f; bi[i] = 0; }
    __syncthreads();
    for (int tile = 0; tile < 16; ++tile) {
        const int mbase = m0 + tile * 128;
        {
            int lrow = tid >> 5, slot = tid & 31;
            for (int p = 0; p < 16; ++p) {
                int row  = p * 8 + lrow;
                float4 v = reinterpret_cast<const float4*>(
                               yd + ((size_t)(b * 4096 + mbase + row)) * 128)[slot];
                int ss = slot ^ (row & 31);
                *reinterpret_cast<float4*>(&Ys[row * 128 + (ss << 2)]) = v;
            }
        }
        __syncthreads();
        float acc[8][8];
        #pragma unroll
        for (int i = 0; i < 8; ++i)
            #pragma unroll
            for (int j = 0; j < 8; ++j) acc[i][j] = 0.0f;
        #pragma unroll 4
        for (int ks = 0; ks < 32; ++ks) {
            float4 bf[8];
            #pragma unroll
            for (int j = 0; j < 8; ++j) {
                int c = j * 16 + tx;
                bf[j] = *reinterpret_cast<const float4*>(&Ys[c * 128 + ((ks ^ (c & 31)) << 2)]);
            }
            #pragma unroll
            for (int i = 0; i < 8; ++i) {
                int r = ty * 8 + i;
                float4 a = *reinterpret_cast<const float4*>(&Xs[r * 128 + ((ks ^ (r & 31)) << 2)]);
                #pragma unroll
                for (int j = 0; j < 8; ++j) {
                    acc[i][j] = fmaf(a.x, bf[j].x, acc[i][j]);
                    acc[i][j] = fmaf(a.y, bf[j].y, acc[i][j]);
                    acc[i][j] = fmaf(a.z, bf[j].z, acc[i][j]);
                    acc[i][j] = fmaf(a.w, bf[j].w, acc[i][j]);
                }
            }
        }
        float y2v[8];
        #pragma unroll
        for (int j = 0; j < 8; ++j) y2v[j] = y2g[mbase + j * 16 + tx];
        #pragma unroll
        for (int i = 0; i < 8; ++i) {
            int r = ty * 8 + i;
            const float* mr = mask + ((size_t)(b * 4096 + row0 + r)) * 4096;
            #pragma unroll
            for (int j = 0; j < 8; ++j) {
                int   m  = mbase + j * 16 + tx;
                float d2 = x2r[i] + y2v[j] - 2.0f * acc[i][j];
                float d  = sqrtf(fmaxf(d2, 0.0f)) * mr[m];
                if (d < bv[i]) { bv[i] = d; bi[i] = m; }
            }
        }
        __syncthreads();
    }
    float* candv = Xs;
    int*   candi = reinterpret_cast<int*>(Xs + 2048);
    #pragma unroll
    for (int i = 0; i < 8; ++i) {
        int r = ty * 8 + i;
        candv[r * 16 + tx] = bv[i];
        candi[r * 16 + tx] = bi[i];
    }
    __syncthreads();
    if (tid < 128) {
        int   r  = tid;
        float v  = candv[r * 16];
        int   ix = candi[r * 16];
        for (int t = 1; t < 16; ++t) {
            float v2 = candv[r * 16 + t];
            int   i2 = candi[r * 16 + t];
            if (v2 < v || (v2 == v && i2 < ix)) { v = v2; ix = i2; }
        }
        int grow = b * 4096 + row0 + r;
        pvals[grow * 2 + mh] = v;
        pidx [grow * 2 + mh] = ix;
    }
}

__global__ __launch_bounds__(256) void k_fin(const float* __restrict__ pvals,
                                             const int* __restrict__ pidx,
                                             float* __restrict__ out) {
    int t = blockIdx.x * 256 + threadIdx.x;
    float v0 = pvals[t * 2], v1 = pvals[t * 2 + 1];
    int   i0 = pidx [t * 2], i1 = pidx [t * 2 + 1];
    bool take1 = (v1 < v0) || (v1 == v0 && i1 < i0);
    float v  = take1 ? v1 : v0;
    int   ix = take1 ? i1 : i0;
    out[67108864 + t]         = (float)ix;
    out[67108864 + 16384 + t] = v;
    out[(size_t)t * 4096 + (size_t)ix] = 1.0f;
}

extern "C" void kernel_launch(void* const* d_in, const int* in_sizes, int n_in,
                              void* d_out, int out_size, void* d_ws, size_t ws_size,
                              hipStream_t stream) {
    const float* xd   = (const float*)d_in[0];
    const float* yd   = (const float*)d_in[1];
    const float* mask = (const float*)d_in[2];
    float* out = (float*)d_out;
    float* wsf = (float*)d_ws;

    const size_t plane_bytes = (size_t)2 * 3 * 4 * 4096 * 128 * 2;   // 25,165,824
    if (ws_size >= 131072 + plane_bytes) {
        unsigned short* pl = (unsigned short*)((char*)d_ws + 131072);
        k_rowsq<<<8192, 256, 0, stream>>>(xd, yd, wsf);
        k_prep <<<2048, 256, 0, stream>>>(xd, yd, pl);
        k_mfma <<<256,  512, 0, stream>>>(mask, wsf, pl, out);
    } else {
        float* pvals = wsf + 32768;
        int*   pidx  = (int*)(wsf + 65536);
        k_rowsq <<<8192, 256, 0, stream>>>(xd, yd, wsf);
        k_main_fb<<<256, 256, 0, stream>>>(xd, yd, mask, wsf, pvals, pidx, out);
        k_fin   <<<64,   256, 0, stream>>>(pvals, pidx, out);
    }
}

// Round 3
// 371.098 us; speedup vs baseline: 1.3983x; 1.2911x over previous
//
#include <hip/hip_runtime.h>

// B=4, N=M=4096, D=128.
// d_out (floats): match_mask [4*4096*4096] | pairs [16384] (as float) | top_dists [16384]
// ws fast path:
//   bytes [0, 131072):        x2 [16384] f32 | y2 [16384] f32
//   bytes [131072, 25296896): planes, 6 x PS elems bf16 (x:h,m,l then y:h,m,l)
//     plane chunk layout: [b(4)][kh(2)][rt(32)] -> 8192-elem (16 KiB) chunk
//     within chunk: [rb(8)][kc(2)][lane(64)][e(8)], value = in[b][rt*128+rb*16+(l&15)][kh*64+kc*32+(l>>4)*8+e]
//   bytes [25296896, 25821184): pv [16384*4] f32 | pi [16384*4] i32  (per-col-quarter argmin partials)
// Extended-K trick: 6 plane products = one K=768 bf16 GEMM with
//   A segs [h,h,m,m,h,l], B segs [h,m,h,m,l,h] -> (hh,hm,mh,mm,hl,lh)

typedef float  f32x4  __attribute__((ext_vector_type(4)));
typedef short  bf16x8 __attribute__((ext_vector_type(8)));

#define PS ((size_t)2097152)   // elems per plane: 4b * 2kh * 32rt * 8192

__device__ __forceinline__ unsigned short f2bf(float x) {
    unsigned u = __float_as_uint(x);
    u += 0x7FFFu + ((u >> 16) & 1u);
    return (unsigned short)(u >> 16);
}
__device__ __forceinline__ float bf2f(unsigned short s) {
    return __uint_as_float(((unsigned)s) << 16);
}
__device__ __forceinline__ void gload_lds16(const void* g, void* l) {
    __builtin_amdgcn_global_load_lds(
        (const __attribute__((address_space(1))) void*)g,
        (__attribute__((address_space(3))) void*)l, 16, 0, 0);
}

__global__ __launch_bounds__(256) void k_rowsq(const float* __restrict__ xd,
                                               const float* __restrict__ yd,
                                               float* __restrict__ ws) {
    int tid  = threadIdx.x;
    int wid  = tid >> 6, lane = tid & 63;
    int gr   = blockIdx.x * 4 + wid;
    const float* src = (gr < 16384) ? (xd + (size_t)gr * 128)
                                    : (yd + (size_t)(gr - 16384) * 128);
    float2 v = reinterpret_cast<const float2*>(src)[lane];
    float s  = v.x * v.x + v.y * v.y;
    for (int off = 32; off > 0; off >>= 1) s += __shfl_down(s, off);
    if (lane == 0) ws[gr] = s;
}

// ---- split f32 -> 3 bf16 planes, packed in 16KiB staging chunks ----
__global__ __launch_bounds__(256) void k_prep(const float* __restrict__ xd,
                                              const float* __restrict__ yd,
                                              unsigned short* __restrict__ pl) {
    int bid  = blockIdx.x;            // 0..2047
    int i    = bid >> 10;             // input 0=x,1=y
    int b    = (bid >> 8) & 3;
    int rblk = bid & 255;             // 16-row block
    int tid  = threadIdx.x;
    int kb   = tid >> 6;              // 0..3
    int l    = tid & 63;
    int r    = rblk * 16 + (l & 15);
    int k0   = kb * 32 + ((l >> 4) & 3) * 8;
    const float* src = (i ? yd : xd) + ((size_t)(b * 4096 + r) * 128 + k0);
    float v[8];
    *reinterpret_cast<float4*>(v)     = *reinterpret_cast<const float4*>(src);
    *reinterpret_cast<float4*>(v + 4) = *reinterpret_cast<const float4*>(src + 4);
    bf16x8 hv, mv, lv;
    #pragma unroll
    for (int e = 0; e < 8; ++e) {
        float x = v[e];
        unsigned short h  = f2bf(x);
        float r1 = x - bf2f(h);
        unsigned short m  = f2bf(r1);
        float r2 = r1 - bf2f(m);
        unsigned short lo = f2bf(r2);
        hv[e] = (short)h; mv[e] = (short)m; lv[e] = (short)lo;
    }
    int rt = rblk >> 3, rb = rblk & 7, kh = kb >> 1, kc = kb & 1;
    size_t base = ((((size_t)((b * 2 + kh) * 32 + rt)) * 8 + rb) * 2 + kc) * 512 + (size_t)l * 8;
    unsigned short* dst = pl + (size_t)(i * 3) * PS;
    *reinterpret_cast<bf16x8*>(dst + base)          = hv;
    *reinterpret_cast<bf16x8*>(dst + base + PS)     = mv;
    *reinterpret_cast<bf16x8*>(dst + base + 2 * PS) = lv;
}

// ---- main: LDS-staged extended-K bf16 GEMM + fused mask/argmin epilogue ----
__global__ __launch_bounds__(256, 2) void k_gemm(const float* __restrict__ mask,
                                                 const float* __restrict__ ws,
                                                 const unsigned short* __restrict__ pl,
                                                 float* __restrict__ out,
                                                 float* __restrict__ pv,
                                                 int* __restrict__ pi) {
    __shared__ __align__(16) unsigned short Abuf[2][8192];   // 2 x 16 KiB
    __shared__ __align__(16) unsigned short Bbuf[2][8192];   // 2 x 16 KiB
    __shared__ float candv[128][2];
    __shared__ int   candi[128][2];

    const int bid = blockIdx.x;        // 512 blocks = 2/CU
    const int xcd = bid & 7;
    const int j   = bid >> 3;          // 0..63
    const int b   = xcd >> 1;          // batch pinned per XCD pair (Y planes L2-resident)
    const int rt  = (xcd & 1) * 16 + (j >> 2);   // row tile 0..31 (128 rows)
    const int cq  = j & 3;             // col quarter (1024 cols)
    const int tid = threadIdx.x;
    const int w   = tid >> 6, l = tid & 63;
    const int wr  = w >> 1, wc = w & 1;          // 2x2 waves of 64x64
    const int g0  = b * 4096 + rt * 128;         // first global row
    const int col0 = cq * 1024;                  // first col (within batch)

    const float* y2 = ws + 16384 + b * 4096;
    float x2r[16];
    #pragma unroll
    for (int mi = 0; mi < 4; ++mi)
        #pragma unroll
        for (int rg = 0; rg < 4; ++rg)
            x2r[mi * 4 + rg] = ws[g0 + wr * 64 + mi * 16 + ((l >> 4) & 3) * 4 + rg];

    float bv[16];
    int   bi[16];
    #pragma unroll
    for (int q = 0; q < 16; ++q) { bv[q] = 3.4e38f; bi[q] = 0; }

    f32x4 acc[4][4];

    auto stage = [&](int ntS, int s, int bsel) {
        int seg = s >> 1, kh = s & 1;
        int sA = (seg == 5) ? 2 : ((seg == 2 || seg == 3) ? 1 : 0);
        int sB = (seg == 4) ? 2 : ((seg == 1 || seg == 3) ? 1 : 0);
        const unsigned short* Ac = pl + (size_t)sA * PS
            + (((size_t)((b * 2 + kh) * 32 + rt)) << 13);
        const unsigned short* Bc = pl + (size_t)(3 + sB) * PS
            + (((size_t)((b * 2 + kh) * 32 + (cq * 8 + ntS))) << 13);
        const char* gA = (const char*)Ac + (size_t)(w * 1024 + l * 16);
        const char* gB = (const char*)Bc + (size_t)(w * 1024 + l * 16);
        char* lA = (char*)(&Abuf[bsel][0]) + w * 1024;
        char* lB = (char*)(&Bbuf[bsel][0]) + w * 1024;
        #pragma unroll
        for (int it = 0; it < 4; ++it) {
            gload_lds16(gA + it * 4096, lA + it * 4096);
            gload_lds16(gB + it * 4096, lB + it * 4096);
        }
    };

    auto compute = [&](int bsel) {
        bf16x8 af[4][2], bfr[4][2];
        #pragma unroll
        for (int mi = 0; mi < 4; ++mi)
            #pragma unroll
            for (int kc = 0; kc < 2; ++kc)
                af[mi][kc] = *reinterpret_cast<const bf16x8*>(
                    &Abuf[bsel][(((wr * 4 + mi) * 2 + kc) * 512) + l * 8]);
        #pragma unroll
        for (int ni = 0; ni < 4; ++ni)
            #pragma unroll
            for (int kc = 0; kc < 2; ++kc)
                bfr[ni][kc] = *reinterpret_cast<const bf16x8*>(
                    &Bbuf[bsel][(((wc * 4 + ni) * 2 + kc) * 512) + l * 8]);
        #pragma unroll
        for (int kc = 0; kc < 2; ++kc)
            #pragma unroll
            for (int mi = 0; mi < 4; ++mi)
                #pragma unroll
                for (int ni = 0; ni < 4; ++ni)
                    acc[mi][ni] = __builtin_amdgcn_mfma_f32_16x16x32_bf16(
                        af[mi][kc], bfr[ni][kc], acc[mi][ni], 0, 0, 0);
    };

    stage(0, 0, 0);
    __syncthreads();

    const float4 zv = make_float4(0.f, 0.f, 0.f, 0.f);
    for (int nt = 0; nt < 8; ++nt) {
        // spread match_mask zeroing: 16 rows per ntile (overlaps compute)
        {
            float4* zp = reinterpret_cast<float4*>(out + (size_t)(g0 + nt * 16) * 4096 + col0);
            #pragma unroll
            for (int r = 0; r < 16; ++r) zp[(size_t)r * 1024 + tid] = zv;
        }
        #pragma unroll
        for (int mi = 0; mi < 4; ++mi)
            #pragma unroll
            for (int ni = 0; ni < 4; ++ni) acc[mi][ni] = (f32x4){0.f, 0.f, 0.f, 0.f};

        #pragma unroll
        for (int s = 0; s < 12; ++s) {
            if (s < 11)      stage(nt, s + 1, (s + 1) & 1);
            else if (nt < 7) stage(nt + 1, 0, 0);
            compute(s & 1);
            if (s == 11) {
                // epilogue: d2 -> dist*mask -> running argmin over this 128-col tile
                #pragma unroll
                for (int ni = 0; ni < 4; ++ni) {
                    int c = col0 + nt * 128 + wc * 64 + ni * 16 + (l & 15);
                    float y2v = y2[c];
                    #pragma unroll
                    for (int mi = 0; mi < 4; ++mi) {
                        #pragma unroll
                        for (int rg = 0; rg < 4; ++rg) {
                            int grow = g0 + wr * 64 + mi * 16 + ((l >> 4) & 3) * 4 + rg;
                            float d2 = x2r[mi * 4 + rg] + y2v - 2.0f * acc[mi][ni][rg];
                            float d  = sqrtf(fmaxf(d2, 0.0f)) * mask[(size_t)grow * 4096 + c];
                            int q = mi * 4 + rg;
                            if (d < bv[q]) { bv[q] = d; bi[q] = c; }
                        }
                    }
                }
            }
            __syncthreads();
        }
    }

    // ---- reduce across the 16 col-lanes, then across the 2 col-waves ----
    #pragma unroll
    for (int off = 1; off < 16; off <<= 1) {
        #pragma unroll
        for (int q = 0; q < 16; ++q) {
            float ov = __shfl_xor(bv[q], off);
            int   oi = __shfl_xor(bi[q], off);
            if (ov < bv[q] || (ov == bv[q] && oi < bi[q])) { bv[q] = ov; bi[q] = oi; }
        }
    }
    if ((l & 15) == 0) {
        #pragma unroll
        for (int mi = 0; mi < 4; ++mi)
            #pragma unroll
            for (int rg = 0; rg < 4; ++rg) {
                int rowl = wr * 64 + mi * 16 + ((l >> 4) & 3) * 4 + rg;
                candv[rowl][wc] = bv[mi * 4 + rg];
                candi[rowl][wc] = bi[mi * 4 + rg];
            }
    }
    __syncthreads();
    if (tid < 128) {
        float v  = candv[tid][0];
        int   ix = candi[tid][0];
        float v2 = candv[tid][1];
        int   i2 = candi[tid][1];
        if (v2 < v || (v2 == v && i2 < ix)) { v = v2; ix = i2; }
        int grow = g0 + tid;
        pv[grow * 4 + cq] = v;
        pi[grow * 4 + cq] = ix;
    }
}

__global__ __launch_bounds__(256) void k_fin(const float* __restrict__ pv,
                                             const int* __restrict__ pi,
                                             float* __restrict__ out) {
    int t = blockIdx.x * 256 + threadIdx.x;   // row 0..16383
    float v  = pv[t * 4];
    int   ix = pi[t * 4];
    #pragma unroll
    for (int q = 1; q < 4; ++q) {
        float v2 = pv[t * 4 + q];
        int   i2 = pi[t * 4 + q];
        if (v2 < v || (v2 == v && i2 < ix)) { v = v2; ix = i2; }
    }
    out[67108864 + t]         = (float)ix;            // pairs
    out[67108864 + 16384 + t] = v;                    // top_dists
    out[(size_t)t * 4096 + (size_t)ix] = 1.0f;        // one-hot
}

// ================= fallback path (needs only 384 KB ws) =================
__global__ __launch_bounds__(256, 1) void k_main_fb(const float* __restrict__ xd,
                                                    const float* __restrict__ yd,
                                                    const float* __restrict__ mask,
                                                    const float* __restrict__ ws,
                                                    float* __restrict__ pvals,
                                                    int* __restrict__ pidx,
                                                    float* __restrict__ mm) {
    __shared__ __align__(16) float Xs[128 * 128];
    __shared__ __align__(16) float Ys[128 * 128];
    const int bid  = blockIdx.x;
    const int mh   = bid & 1;
    const int rb   = (bid >> 1) & 31;
    const int b    = bid >> 6;
    const int tid  = threadIdx.x;
    const int ty   = tid >> 4;
    const int tx   = tid & 15;
    const int row0 = rb * 128;
    const int m0   = mh * 2048;
    {
        const float4 z = make_float4(0.f, 0.f, 0.f, 0.f);
        size_t base = ((size_t)(b * 4096 + row0)) * 4096 + (size_t)m0;
        for (int r = 0; r < 128; ++r) {
            float4* p = reinterpret_cast<float4*>(mm + base + (size_t)r * 4096);
            p[tid] = z; p[tid + 256] = z;
        }
    }
    {
        int lrow = tid >> 5, slot = tid & 31;
        for (int p = 0; p < 16; ++p) {
            int row  = p * 8 + lrow;
            float4 v = reinterpret_cast<const float4*>(
                           xd + ((size_t)(b * 4096 + row0 + row)) * 128)[slot];
            int ss = slot ^ (row & 31);
            *reinterpret_cast<float4*>(&Xs[row * 128 + (ss << 2)]) = v;
        }
    }
    float x2r[8];
    #pragma unroll
    for (int i = 0; i < 8; ++i) x2r[i] = ws[b * 4096 + row0 + ty * 8 + i];
    const float* y2g = ws + 16384 + b * 4096;
    float bv[8]; int bi[8];
    #pragma unroll
    for (int i = 0; i < 8; ++i) { bv[i] = 3.4e38f; bi[i] = 0; }
    __syncthreads();
    for (int tile = 0; tile < 16; ++tile) {
        const int mbase = m0 + tile * 128;
        {
            int lrow = tid >> 5, slot = tid & 31;
            for (int p = 0; p < 16; ++p) {
                int row  = p * 8 + lrow;
                float4 v = reinterpret_cast<const float4*>(
                               yd + ((size_t)(b * 4096 + mbase + row)) * 128)[slot];
                int ss = slot ^ (row & 31);
                *reinterpret_cast<float4*>(&Ys[row * 128 + (ss << 2)]) = v;
            }
        }
        __syncthreads();
        float acc[8][8];
        #pragma unroll
        for (int i = 0; i < 8; ++i)
            #pragma unroll
            for (int jj = 0; jj < 8; ++jj) acc[i][jj] = 0.0f;
        #pragma unroll 4
        for (int ks = 0; ks < 32; ++ks) {
            float4 bf[8];
            #pragma unroll
            for (int jj = 0; jj < 8; ++jj) {
                int c = jj * 16 + tx;
                bf[jj] = *reinterpret_cast<const float4*>(&Ys[c * 128 + ((ks ^ (c & 31)) << 2)]);
            }
            #pragma unroll
            for (int i = 0; i < 8; ++i) {
                int r = ty * 8 + i;
                float4 a = *reinterpret_cast<const float4*>(&Xs[r * 128 + ((ks ^ (r & 31)) << 2)]);
                #pragma unroll
                for (int jj = 0; jj < 8; ++jj) {
                    acc[i][jj] = fmaf(a.x, bf[jj].x, acc[i][jj]);
                    acc[i][jj] = fmaf(a.y, bf[jj].y, acc[i][jj]);
                    acc[i][jj] = fmaf(a.z, bf[jj].z, acc[i][jj]);
                    acc[i][jj] = fmaf(a.w, bf[jj].w, acc[i][jj]);
                }
            }
        }
        float y2v[8];
        #pragma unroll
        for (int jj = 0; jj < 8; ++jj) y2v[jj] = y2g[mbase + jj * 16 + tx];
        #pragma unroll
        for (int i = 0; i < 8; ++i) {
            int r = ty * 8 + i;
            const float* mr = mask + ((size_t)(b * 4096 + row0 + r)) * 4096;
            #pragma unroll
            for (int jj = 0; jj < 8; ++jj) {
                int   m  = mbase + jj * 16 + tx;
                float d2 = x2r[i] + y2v[jj] - 2.0f * acc[i][jj];
                float d  = sqrtf(fmaxf(d2, 0.0f)) * mr[m];
                if (d < bv[i]) { bv[i] = d; bi[i] = m; }
            }
        }
        __syncthreads();
    }
    float* candv = Xs;
    int*   candi = reinterpret_cast<int*>(Xs + 2048);
    #pragma unroll
    for (int i = 0; i < 8; ++i) {
        int r = ty * 8 + i;
        candv[r * 16 + tx] = bv[i];
        candi[r * 16 + tx] = bi[i];
    }
    __syncthreads();
    if (tid < 128) {
        int   r  = tid;
        float v  = candv[r * 16];
        int   ix = candi[r * 16];
        for (int t = 1; t < 16; ++t) {
            float v2 = candv[r * 16 + t];
            int   i2 = candi[r * 16 + t];
            if (v2 < v || (v2 == v && i2 < ix)) { v = v2; ix = i2; }
        }
        int grow = b * 4096 + row0 + r;
        pvals[grow * 2 + mh] = v;
        pidx [grow * 2 + mh] = ix;
    }
}

__global__ __launch_bounds__(256) void k_fin_fb(const float* __restrict__ pvals,
                                                const int* __restrict__ pidx,
                                                float* __restrict__ out) {
    int t = blockIdx.x * 256 + threadIdx.x;
    float v0 = pvals[t * 2], v1 = pvals[t * 2 + 1];
    int   i0 = pidx [t * 2], i1 = pidx [t * 2 + 1];
    bool take1 = (v1 < v0) || (v1 == v0 && i1 < i0);
    float v  = take1 ? v1 : v0;
    int   ix = take1 ? i1 : i0;
    out[67108864 + t]         = (float)ix;
    out[67108864 + 16384 + t] = v;
    out[(size_t)t * 4096 + (size_t)ix] = 1.0f;
}

extern "C" void kernel_launch(void* const* d_in, const int* in_sizes, int n_in,
                              void* d_out, int out_size, void* d_ws, size_t ws_size,
                              hipStream_t stream) {
    const float* xd   = (const float*)d_in[0];
    const float* yd   = (const float*)d_in[1];
    const float* mask = (const float*)d_in[2];
    float* out = (float*)d_out;
    float* wsf = (float*)d_ws;

    const size_t need = 131072 + 6 * PS * 2 + 524288;   // 25,821,184
    if (ws_size >= need) {
        unsigned short* pl = (unsigned short*)((char*)d_ws + 131072);
        float* pv = (float*)((char*)d_ws + 131072 + 6 * PS * 2);
        int*   pi = (int*)  ((char*)d_ws + 131072 + 6 * PS * 2 + 262144);
        k_rowsq<<<8192, 256, 0, stream>>>(xd, yd, wsf);
        k_prep <<<2048, 256, 0, stream>>>(xd, yd, pl);
        k_gemm <<<512,  256, 0, stream>>>(mask, wsf, pl, out, pv, pi);
        k_fin  <<<64,   256, 0, stream>>>(pv, pi, out);
    } else {
        float* pvals = wsf + 32768;
        int*   pidx  = (int*)(wsf + 65536);
        k_rowsq  <<<8192, 256, 0, stream>>>(xd, yd, wsf);
        k_main_fb<<<256,  256, 0, stream>>>(xd, yd, mask, wsf, pvals, pidx, out);
        k_fin_fb <<<64,   256, 0, stream>>>(pvals, pidx, out);
    }
}